// Round 9
// baseline (82.240 us; speedup 1.0000x reference)
//
#include <hip/hip_runtime.h>
#include <math.h>

// SE layer: x[32,256,64,64] f32, w1[16,256], w2[256,256]
// pooled = mean(x, HW); y = relu(pooled @ w1^T); outer = y⊗y (flat 256);
// s = sigmoid(outer @ w2^T); out = x * s[b,c]
//
// L2-sized chunk pipeline: per 4-batch chunk (16.8 MB = 2.1 MB/XCD << 4 MB
// per-XCD L2), pool(chunk) then scale(chunk) back-to-back. Both kernels use
// identical 1024-block grids and identical bid->slice maps, so each slice is
// touched by the SAME bid (= same XCD) in both passes -> the scale pass's
// x re-read hits that XCD's L2 (34.5 TB/s) instead of HBM. out uses nt
// stores (no L2 pollution). fc chain recomputed per scale block (cheap,
// round-6-proven). Rounds 4/6/8 showed L3 hits cost ~HBM time on MI355X,
// so L2 is the only cache worth targeting.

#define B 32
#define C 256
#define HID 16
#define BD 256       // HID*HID
#define HW 4096      // 64*64
#define CHUNKB 4     // batches per chunk: 4*256*16KB = 16.8 MB -> 2.1 MB/XCD

typedef float vf4 __attribute__((ext_vector_type(4)));

// ---------------- pool: one block per (b,c) slice ----------------
__global__ __launch_bounds__(256) void pool_kernel(const float* __restrict__ x,
                                                   float* __restrict__ pooled,
                                                   int bc0) {
    const int bc = bc0 + blockIdx.x;
    const vf4* xp = reinterpret_cast<const vf4*>(x + (size_t)bc * HW);
    const int t = threadIdx.x;
    float sum = 0.f;
#pragma unroll
    for (int k = 0; k < 4; ++k) {
        vf4 v = xp[t + k * 256];   // plain loads: allocate in this XCD's L2
        sum += (v.x + v.y) + (v.z + v.w);
    }
#pragma unroll
    for (int off = 32; off > 0; off >>= 1) sum += __shfl_down(sum, off, 64);
    __shared__ float red[4];
    if ((t & 63) == 0) red[t >> 6] = sum;
    __syncthreads();
    if (t == 0)
        pooled[bc] = ((red[0] + red[1]) + (red[2] + red[3])) * (1.0f / (float)HW);
}

// ------- scale: one block per (b,c); recomputes fc for its channel -------
__global__ __launch_bounds__(256) void scale_kernel(const float* __restrict__ x,
                                                    const float* __restrict__ pooled,
                                                    const float* __restrict__ w1,
                                                    const float* __restrict__ w2,
                                                    float* __restrict__ out,
                                                    int bc0) {
    const int bc = bc0 + blockIdx.x;        // same bid->slice map as pool
    const int b = bc >> 8, c0 = bc & 255;
    const int t = threadIdx.x;

    // issue x loads early (should hit this XCD's L2); fc hides latency
    const vf4* xp = reinterpret_cast<const vf4*>(x + (size_t)bc * HW);
    vf4 v0 = xp[t];
    vf4 v1 = xp[t + 256];
    vf4 v2 = xp[t + 512];
    vf4 v3 = xp[t + 768];

    __shared__ float pl[C];
    __shared__ float yv[HID];
    __shared__ float red[4];
    __shared__ float sc_sh;

    pl[t] = pooled[b * C + t];
    __syncthreads();

    // fc1 + relu: h = t>>4, 16 lanes per h each sum 16 c's, shfl-reduce
    {
        const int h = t >> 4, j = t & 15;
        const float* w1r = w1 + h * C + j * 16;
        const float* plr = pl + j * 16;
        float p = 0.f;
#pragma unroll
        for (int k = 0; k < 16; ++k) p += plr[k] * w1r[k];
        p += __shfl_xor(p, 1, 64);
        p += __shfl_xor(p, 2, 64);
        p += __shfl_xor(p, 4, 64);
        p += __shfl_xor(p, 8, 64);
        if (j == 0) yv[h] = fmaxf(p, 0.f);
    }
    __syncthreads();

    // fc2 for this block's channel c0: block-reduce 256 terms
    float term = yv[t >> 4] * yv[t & 15] * w2[(size_t)c0 * BD + t];
#pragma unroll
    for (int off = 32; off > 0; off >>= 1) term += __shfl_down(term, off, 64);
    if ((t & 63) == 0) red[t >> 6] = term;
    __syncthreads();
    if (t == 0)
        sc_sh = 1.0f / (1.0f + expf(-((red[0] + red[1]) + (red[2] + red[3]))));
    __syncthreads();
    const float sc = sc_sh;

    vf4* op = reinterpret_cast<vf4*>(out + (size_t)bc * HW);
    v0 *= sc; v1 *= sc; v2 *= sc; v3 *= sc;
    __builtin_nontemporal_store(v0, &op[t]);
    __builtin_nontemporal_store(v1, &op[t + 256]);
    __builtin_nontemporal_store(v2, &op[t + 512]);
    __builtin_nontemporal_store(v3, &op[t + 768]);
}

extern "C" void kernel_launch(void* const* d_in, const int* in_sizes, int n_in,
                              void* d_out, int out_size, void* d_ws, size_t ws_size,
                              hipStream_t stream) {
    const float* x  = (const float*)d_in[0];
    const float* w1 = (const float*)d_in[1];
    const float* w2 = (const float*)d_in[2];
    float* out = (float*)d_out;

    float* pooled = (float*)d_ws;   // B*C floats (32 KB)

    for (int cb = 0; cb < B; cb += CHUNKB) {
        const int bc0 = cb * C;
        pool_kernel<<<CHUNKB * C, 256, 0, stream>>>(x, pooled, bc0);
        scale_kernel<<<CHUNKB * C, 256, 0, stream>>>(x, pooled, w1, w2, out, bc0);
    }
}